// Round 6
// baseline (218.887 us; speedup 1.0000x reference)
//
#include <hip/hip_runtime.h>
#include <cstdint>

#define CD 64
#define HWD 589824
#define NSAMP 8192
#define STILES (NSAMP / 32)         // 256
#define PAD_TAU 0.25f
#define NTILE 32
#define TILES (HWD / NTILE)         // 18432
#define K1_BLOCKS 1536
#define K1_WAVES (K1_BLOCKS * 4)    // 6144
#define TPW (TILES / K1_WAVES)      // 3
#define W2 (K1_WAVES * 2)           // 12288 cell rows
#define NW2A 512                    // k2a waves
#define K2A_BLOCKS (NW2A / 4)       // 128
#define RPW (W2 / NW2A)             // 24 rows per k2a wave
#define NW0B 128                    // k0b waves
#define K0B_BLOCKS (NW0B / 4)       // 32
#define RPW0 (NSAMP / NW0B)         // 64 rows per k0b wave
#define FMAXV 3.402823466e+38f

typedef float f32x16 __attribute__((ext_vector_type(16)));
typedef short bf16x8 __attribute__((ext_vector_type(8)));

__device__ __forceinline__ short f2bf(float f) {
    unsigned u = __float_as_uint(f);
    u = u + 0x7FFFu + ((u >> 16) & 1u);   // RNE
    return (short)(u >> 16);
}

// exact 16-smallest screen (static indexing only)
#define SCREEN(d, lst, cm)                                                  \
    if ((d) < (cm)) {                                                       \
        bool rep = false;                                                   \
        _Pragma("unroll")                                                   \
        for (int j = 0; j < 16; ++j)                                        \
            if (!rep && lst[j] == (cm)) { lst[j] = (d); rep = true; }       \
        cm = lst[0];                                                        \
        _Pragma("unroll")                                                   \
        for (int j = 1; j < 16; ++j) cm = fmaxf(cm, lst[j]);                \
    }

// wave-level exact 16-smallest extraction from per-lane lst[16]; returns
// sum of the 16 smallest; records the 16th smallest in *p16.
__device__ __forceinline__ float wave_extract16(float* lst, int lane, float* p16)
{
    float sum = 0.f, last = 0.f;
    for (int r = 0; r < 16; ++r) {
        float mn = lst[0]; int a = 0;
#pragma unroll
        for (int j = 1; j < 16; ++j) if (lst[j] < mn) { mn = lst[j]; a = j; }
        unsigned long long key =
            ((unsigned long long)__float_as_uint(mn) << 32) | (unsigned)(lane * 16 + a);
#pragma unroll
        for (int off = 32; off; off >>= 1) {
            unsigned long long o = __shfl_xor(key, off);
            if (o < key) key = o;
        }
        last = __uint_as_float((unsigned)(key >> 32));
        sum += last;
        int slot = (int)(key & 0xFFFFFFFFu);
        if ((slot >> 4) == lane) {
#pragma unroll
            for (int j = 0; j < 16; ++j) if (j == (slot & 15)) lst[j] = FMAXV;
        }
    }
    *p16 = last;
    return sum;
}

// Shared tile engine: d(p, n0+.) for 32 columns x 64 p.
__device__ __forceinline__ void tile_dist(
    const float* __restrict__ fp,          // f2 + n0 + l31
    const bf16x8* __restrict__ sf0, const bf16x8* __restrict__ sf1,
    int lh, f32x16& acc0, f32x16& acc1, float& fs)
{
    fs = 0.f;
#pragma unroll
    for (int i = 0; i < 16; ++i) { acc0[i] = 0.f; acc1[i] = 0.f; }
#pragma unroll
    for (int ks = 0; ks < 4; ++ks) {
        float av[8];
#pragma unroll
        for (int j = 0; j < 8; ++j)
            av[j] = fp[(long)(16 * ks + 8 * lh + j) * HWD];
        bf16x8 af;
#pragma unroll
        for (int j = 0; j < 8; ++j) {
            fs += av[j] * av[j];
            af[j] = f2bf(av[j]);
        }
        acc0 = __builtin_amdgcn_mfma_f32_32x32x16_bf16(af, sf0[ks], acc0, 0, 0, 0);
        acc1 = __builtin_amdgcn_mfma_f32_32x32x16_bf16(af, sf1[ks], acc1, 0, 0, 0);
    }
    fs += __shfl_xor(fs, 32);   // combine k-halves (same column n)
}

// k_pack: one wave packs sel bf16 B-fragments + ||sel||^2.
__global__ void k_pack(const float* __restrict__ f1, const int* __restrict__ nidx,
                       bf16x8* __restrict__ selpack, float* __restrict__ sel2p)
{
    const int lane = threadIdx.x;          // 64 threads
    const int l31 = lane & 31, lh = lane >> 5;
#pragma unroll
    for (int b = 0; b < 2; ++b) {
        long colb = (long)nidx[l31 + 32 * b];
        float s2 = 0.f;
#pragma unroll
        for (int ks = 0; ks < 4; ++ks) {
            bf16x8 fr;
#pragma unroll
            for (int j = 0; j < 8; ++j) {
                float v = f1[(long)(16 * ks + 8 * lh + j) * HWD + colb];
                s2 += v * v;
                fr[j] = f2bf(v);
            }
            selpack[(b * 4 + ks) * 64 + lane] = fr;
        }
        s2 += __shfl_xor(s2, 32);
        sel2p[b * 64 + lane] = s2;
    }
}

// k0a: 256 one-wave blocks over the first 8192 columns; writes dsT[n][p].
__global__ __launch_bounds__(64) void k0a_sample(
    const float* __restrict__ f2, const bf16x8* __restrict__ selpack,
    const float* __restrict__ sel2p, float* __restrict__ dsT)
{
    const int lane = threadIdx.x;
    const int l31 = lane & 31, lh = lane >> 5;
    const long n0 = (long)blockIdx.x * NTILE;

    bf16x8 sf0[4], sf1[4];
#pragma unroll
    for (int ks = 0; ks < 4; ++ks) {
        sf0[ks] = selpack[ks * 64 + lane];
        sf1[ks] = selpack[(4 + ks) * 64 + lane];
    }
    const float sel20 = sel2p[lane], sel21 = sel2p[64 + lane];

    f32x16 acc0, acc1; float fs;
    tile_dist(f2 + n0 + l31, sf0, sf1, lh, acc0, acc1, fs);

#pragma unroll
    for (int i = 0; i < 16; ++i) {
        int r = (i & 3) + 8 * (i >> 2) + 4 * lh;
        float fr2 = __shfl(fs, r);
        dsT[(n0 + r) * 64 + l31]      = fmaxf(sel20 + fr2 - 2.f * acc0[i], 0.f);
        dsT[(n0 + r) * 64 + 32 + l31] = fmaxf(sel21 + fr2 - 2.f * acc1[i], 0.f);
    }
}

// k0b: 128 waves; wave w screens rows [w*64, w*64+64) of dsT; lane l owns p=l.
// Coalesced 256B row reads. Emits cand0[p][w][16] (FMAXV-padded).
__global__ __launch_bounds__(256) void k0b_screen(
    const float* __restrict__ dsT, float* __restrict__ cand0)
{
    const int lane = threadIdx.x & 63;
    const int w = blockIdx.x * 4 + (threadIdx.x >> 6);   // 0..127

    float lst[16];
#pragma unroll
    for (int j = 0; j < 16; ++j) lst[j] = FMAXV;
    float cm = FMAXV;

    const float* base = dsT + (long)w * RPW0 * 64 + lane;
#pragma unroll 8
    for (int r = 0; r < RPW0; ++r) {
        float d = base[r * 64];
        SCREEN(d, lst, cm);
    }

    float4* o = (float4*)(cand0 + ((long)lane * NW0B + w) * 16);
#pragma unroll
    for (int q = 0; q < 4; ++q)
        o[q] = make_float4(lst[4*q], lst[4*q+1], lst[4*q+2], lst[4*q+3]);
}

// k0c: one wave per p. 2048 candidates -> exact 16th smallest -> tau.
__global__ __launch_bounds__(64) void k0c_tau(
    const float* __restrict__ cand0, float* __restrict__ tau)
{
    const int p = blockIdx.x;
    const int lane = threadIdx.x;
    const float4* base = (const float4*)(cand0 + (long)p * NW0B * 16);

    float lst[16];
#pragma unroll
    for (int j = 0; j < 16; ++j) lst[j] = FMAXV;
    float cm = FMAXV;
#pragma unroll
    for (int k = 0; k < NW0B * 16 / 4 / 64; ++k) {   // 8
        float4 v = base[k * 64 + lane];
        SCREEN(v.x, lst, cm);
        SCREEN(v.y, lst, cm);
        SCREEN(v.z, lst, cm);
        SCREEN(v.w, lst, cm);
    }
    float p16;
    wave_extract16(lst, lane, &p16);
    if (lane == 0) tau[p] = p16 + PAD_TAU;
}

// K1: stream f2, MFMA distances, filter vs tau into dense FMAXV-filled float4
// cells surv4[row = gw*2+lh][col = p] (coalesced stores, no cnt, no atomics).
__global__ __launch_bounds__(256) void k1_dist(
    const float* __restrict__ f2, const bf16x8* __restrict__ selpack,
    const float* __restrict__ sel2p, const float* __restrict__ tau,
    float4* __restrict__ surv4)
{
    const int tid = threadIdx.x;
    const int lane = tid & 63, wid = tid >> 6;
    const int l31 = lane & 31, lh = lane >> 5;
    const int gw = blockIdx.x * 4 + wid;        // 0..6143

    bf16x8 sf0[4], sf1[4];
#pragma unroll
    for (int ks = 0; ks < 4; ++ks) {
        sf0[ks] = selpack[ks * 64 + lane];
        sf1[ks] = selpack[(4 + ks) * 64 + lane];
    }
    const float sel20 = sel2p[lane], sel21 = sel2p[64 + lane];
    const float tau0 = tau[l31], tau1 = tau[l31 + 32];

    float4 v0 = make_float4(FMAXV, FMAXV, FMAXV, FMAXV);
    float4 v1 = v0;
    unsigned c0 = 0, c1 = 0;

    for (int t = 0; t < TPW; ++t) {
        const long n0 = (long)(gw * TPW + t) * NTILE;
        f32x16 acc0, acc1; float fs;
        tile_dist(f2 + n0 + l31, sf0, sf1, lh, acc0, acc1, fs);

#pragma unroll
        for (int i = 0; i < 16; ++i) {
            int r = (i & 3) + 8 * (i >> 2) + 4 * lh;
            float fr2 = __shfl(fs, r);
            float d0 = fmaxf(sel20 + fr2 - 2.f * acc0[i], 0.f);
            if (d0 <= tau0) {
                if (c0 == 0) v0.x = d0; else if (c0 == 1) v0.y = d0;
                else if (c0 == 2) v0.z = d0; else if (c0 == 3) v0.w = d0;
                ++c0;
            }
            float d1 = fmaxf(sel21 + fr2 - 2.f * acc1[i], 0.f);
            if (d1 <= tau1) {
                if (c1 == 0) v1.x = d1; else if (c1 == 1) v1.y = d1;
                else if (c1 == 2) v1.z = d1; else if (c1 == 3) v1.w = d1;
                ++c1;
            }
        }
    }
    float4* srow = surv4 + ((long)gw * 2 + lh) * 64;
    srow[l31]      = v0;   // p = l31
    srow[l31 + 32] = v1;   // p = l31 + 32
}

// k2a: 512 waves. Wave reads 24 coalesced 1KB rows of surv4[W2][64];
// lane l screens column p=l into a register top-16. Emits cand2[p][wv][16].
__global__ __launch_bounds__(256) void k2a_screen(
    const float4* __restrict__ surv4, float* __restrict__ cand2)
{
    const int lane = threadIdx.x & 63;
    const int wv = blockIdx.x * 4 + (threadIdx.x >> 6);   // 0..511

    float lst[16];
#pragma unroll
    for (int j = 0; j < 16; ++j) lst[j] = FMAXV;
    float cm = FMAXV;

    const float4* base = surv4 + (long)wv * RPW * 64 + lane;
#pragma unroll 8
    for (int r = 0; r < RPW; ++r) {
        float4 v = base[r * 64];
        SCREEN(v.x, lst, cm);
        SCREEN(v.y, lst, cm);
        SCREEN(v.z, lst, cm);
        SCREEN(v.w, lst, cm);
    }

    float4* o = (float4*)(cand2 + ((long)lane * NW2A + wv) * 16);
#pragma unroll
    for (int q = 0; q < 4; ++q)
        o[q] = make_float4(lst[4*q], lst[4*q+1], lst[4*q+2], lst[4*q+3]);
}

// k2b: one wave per p. 8192 candidates -> exact top-16 sum.
__global__ __launch_bounds__(64) void k2b_select(
    const float* __restrict__ cand2, float* __restrict__ partial)
{
    const int p = blockIdx.x;
    const int lane = threadIdx.x;
    const float4* base = (const float4*)(cand2 + (long)p * NW2A * 16);

    float lst[16];
#pragma unroll
    for (int j = 0; j < 16; ++j) lst[j] = FMAXV;
    float cm = FMAXV;
#pragma unroll 8
    for (int k = 0; k < NW2A * 16 / 4 / 64; ++k) {   // 32
        float4 v = base[k * 64 + lane];
        SCREEN(v.x, lst, cm);
        SCREEN(v.y, lst, cm);
        SCREEN(v.z, lst, cm);
        SCREEN(v.w, lst, cm);
    }
    float p16;
    float sum = wave_extract16(lst, lane, &p16);
    if (lane == 0) partial[p] = sum;
}

__global__ void k3_final(const float* __restrict__ partial, float* __restrict__ out)
{
    float v = partial[threadIdx.x];   // 64 threads
#pragma unroll
    for (int off = 32; off; off >>= 1) v += __shfl_xor(v, off);
    if (threadIdx.x == 0) out[0] = -v / 1024.0f;
}

extern "C" void kernel_launch(void* const* d_in, const int* in_sizes, int n_in,
                              void* d_out, int out_size, void* d_ws, size_t ws_size,
                              hipStream_t stream)
{
    const float* f1   = (const float*)d_in[0];
    const float* f2   = (const float*)d_in[1];
    const int*   nidx = (const int*)d_in[3];     // negative_indices
    float* out = (float*)d_out;

    float4* surv4 = (float4*)d_ws;                       // 12288*64*16 B = 12.6 MB
    float*  dsT   = (float*)d_ws;                        // 2 MB, aliases surv4
                                                         // (consumed before k1 writes)
    float*  cand2 = (float*)(surv4 + (long)W2 * 64);     // 64*512*16 fl = 2 MB
    float*  cand0 = cand2 + (long)CD * NW2A * 16;        // 64*128*16 fl = 0.5 MB
    bf16x8* selpack = (bf16x8*)(cand0 + (long)CD * NW0B * 16);   // 8 KB
    float*  sel2p = (float*)(selpack + 8 * 64);
    float*  tau   = sel2p + 128;
    float*  partial = tau + CD;

    k_pack    <<<1,          64, 0, stream>>>(f1, nidx, selpack, sel2p);
    k0a_sample<<<STILES,     64, 0, stream>>>(f2, selpack, sel2p, dsT);
    k0b_screen<<<K0B_BLOCKS,256, 0, stream>>>(dsT, cand0);
    k0c_tau   <<<CD,         64, 0, stream>>>(cand0, tau);
    k1_dist   <<<K1_BLOCKS, 256, 0, stream>>>(f2, selpack, sel2p, tau, surv4);
    k2a_screen<<<K2A_BLOCKS,256, 0, stream>>>(surv4, cand2);
    k2b_select<<<CD,         64, 0, stream>>>(cand2, partial);
    k3_final  <<<1,          64, 0, stream>>>(partial, out);
}

// Round 7
// 187.392 us; speedup vs baseline: 1.1681x; 1.1681x over previous
//
#include <hip/hip_runtime.h>
#include <cstdint>

#define CD 64
#define HWD 589824
#define NSAMP 65536
#define SWAVES (NSAMP / 32)         // 2048
#define KB_BLOCKS (SWAVES / 4)      // 512
#define PAD_TAU 0.25f
#define NTILE 32
#define TILES (HWD / NTILE)         // 18432
#define K1_BLOCKS 1536
#define K1_WAVES (K1_BLOCKS * 4)    // 6144
#define TPW (TILES / K1_WAVES)      // 3
#define W2 (K1_WAVES * 2)           // 12288 cell rows
#define NW2A 512                    // k2a waves
#define K2A_BLOCKS (NW2A / 4)       // 128
#define RPW (W2 / NW2A)             // 24 rows per k2a wave
#define FMAXV 3.402823466e+38f

typedef float f32x16 __attribute__((ext_vector_type(16)));
typedef short bf16x8 __attribute__((ext_vector_type(8)));

__device__ __forceinline__ short f2bf(float f) {
    unsigned u = __float_as_uint(f);
    u = u + 0x7FFFu + ((u >> 16) & 1u);   // RNE
    return (short)(u >> 16);
}

// exact 16-smallest screen (static indexing only)
#define SCREEN(d, lst, cm)                                                  \
    if ((d) < (cm)) {                                                       \
        bool rep = false;                                                   \
        _Pragma("unroll")                                                   \
        for (int j = 0; j < 16; ++j)                                        \
            if (!rep && lst[j] == (cm)) { lst[j] = (d); rep = true; }       \
        cm = lst[0];                                                        \
        _Pragma("unroll")                                                   \
        for (int j = 1; j < 16; ++j) cm = fmaxf(cm, lst[j]);                \
    }

// block-wide exact 16-smallest extraction from per-thread lst[16].
__device__ __forceinline__ void block_extract16(
    float* lst, int tid, int nwaves, unsigned long long* wmin,
    float* sum_out, float* p16_out)
{
    const int lane = tid & 63, wid = tid >> 6;
    float sum = 0.f, last = 0.f;
    for (int r = 0; r < 16; ++r) {
        float mn = lst[0]; int a = 0;
#pragma unroll
        for (int j = 1; j < 16; ++j) if (lst[j] < mn) { mn = lst[j]; a = j; }
        unsigned long long key =
            ((unsigned long long)__float_as_uint(mn) << 32) | (unsigned)(tid * 16 + a);
#pragma unroll
        for (int off = 32; off; off >>= 1) {
            unsigned long long o = __shfl_xor(key, off);
            if (o < key) key = o;
        }
        if (lane == 0) wmin[wid] = key;
        __syncthreads();
        unsigned long long gk = wmin[0];
        for (int w = 1; w < nwaves; ++w) if (wmin[w] < gk) gk = wmin[w];
        last = __uint_as_float((unsigned)(gk >> 32));
        sum += last;
        int slot = (int)(gk & 0xFFFFFFFFu);
        if ((slot >> 4) == tid) {
#pragma unroll
            for (int j = 0; j < 16; ++j) if (j == (slot & 15)) lst[j] = FMAXV;
        }
        __syncthreads();
    }
    *sum_out = sum; *p16_out = last;
}

// Shared tile engine: d(p, n0+.) for 32 columns x 64 p.
__device__ __forceinline__ void tile_dist(
    const float* __restrict__ fp,          // f2 + n0 + l31
    const bf16x8* __restrict__ sf0, const bf16x8* __restrict__ sf1,
    int lh, f32x16& acc0, f32x16& acc1, float& fs)
{
    fs = 0.f;
#pragma unroll
    for (int i = 0; i < 16; ++i) { acc0[i] = 0.f; acc1[i] = 0.f; }
#pragma unroll
    for (int ks = 0; ks < 4; ++ks) {
        float av[8];
#pragma unroll
        for (int j = 0; j < 8; ++j)
            av[j] = fp[(long)(16 * ks + 8 * lh + j) * HWD];
        bf16x8 af;
#pragma unroll
        for (int j = 0; j < 8; ++j) {
            fs += av[j] * av[j];
            af[j] = f2bf(av[j]);
        }
        acc0 = __builtin_amdgcn_mfma_f32_32x32x16_bf16(af, sf0[ks], acc0, 0, 0, 0);
        acc1 = __builtin_amdgcn_mfma_f32_32x32x16_bf16(af, sf1[ks], acc1, 0, 0, 0);
    }
    fs += __shfl_xor(fs, 32);   // combine k-halves (same column n)
}

__device__ __forceinline__ void load_selfrag(
    const short* __restrict__ sel_bf, int l31, int lh, bf16x8* sf0, bf16x8* sf1)
{
#pragma unroll
    for (int ks = 0; ks < 4; ++ks) {
        sf0[ks] = *(const bf16x8*)(sel_bf + l31 * 64 + 16 * ks + 8 * lh);
        sf1[ks] = *(const bf16x8*)(sel_bf + (l31 + 32) * 64 + 16 * ks + 8 * lh);
    }
}

// kA: 64 blocks x 64 threads; thread k of block p loads one sel element.
__global__ __launch_bounds__(64) void kA_pack(
    const float* __restrict__ f1, const int* __restrict__ nidx,
    short* __restrict__ sel_bf, float* __restrict__ sel2)
{
    const int p = blockIdx.x, k = threadIdx.x;
    float v = f1[(long)k * HWD + nidx[p]];
    float s = v * v;
#pragma unroll
    for (int off = 32; off; off >>= 1) s += __shfl_xor(s, off);
    sel_bf[p * 64 + k] = f2bf(v);
    if (k == 0) sel2[p] = s;
}

// kB: 2048 waves; wave gw computes sample tile gw (cols gw*32..) and writes
// dsP[p][n] (row-major per p -> kC reads contiguously).
__global__ __launch_bounds__(256) void kB_sample(
    const float* __restrict__ f2, const short* __restrict__ sel_bf,
    const float* __restrict__ sel2, float* __restrict__ dsP)
{
    const int tid = threadIdx.x;
    const int lane = tid & 63, wid = tid >> 6;
    const int l31 = lane & 31, lh = lane >> 5;
    const int gw = blockIdx.x * 4 + wid;      // 0..2047
    const long n0 = (long)gw * NTILE;

    bf16x8 sf0[4], sf1[4];
    load_selfrag(sel_bf, l31, lh, sf0, sf1);
    const float sel20 = sel2[l31], sel21 = sel2[l31 + 32];

    f32x16 acc0, acc1; float fs;
    tile_dist(f2 + n0 + l31, sf0, sf1, lh, acc0, acc1, fs);

#pragma unroll
    for (int i = 0; i < 16; ++i) {
        int r = (i & 3) + 8 * (i >> 2) + 4 * lh;
        float fr2 = __shfl(fs, r);
        dsP[(long)l31 * NSAMP + n0 + r]        = fmaxf(sel20 + fr2 - 2.f * acc0[i], 0.f);
        dsP[(long)(l31 + 32) * NSAMP + n0 + r] = fmaxf(sel21 + fr2 - 2.f * acc1[i], 0.f);
    }
}

// kC: 64 blocks x 1024 threads; block p reduces dsP[p][0..65535] -> tau[p].
__global__ __launch_bounds__(1024) void kC_tau(
    const float* __restrict__ dsP, float* __restrict__ tau)
{
    const int p = blockIdx.x;
    const int tid = threadIdx.x;
    __shared__ unsigned long long wmin[16];

    float lst[16];
#pragma unroll
    for (int j = 0; j < 16; ++j) lst[j] = FMAXV;
    float cm = FMAXV;

    const float* base = dsP + (long)p * NSAMP;
#pragma unroll 8
    for (int i = 0; i < NSAMP / 1024; ++i) {   // 64 coalesced loads
        float d = base[tid + i * 1024];
        SCREEN(d, lst, cm);
    }
    float sum, p16;
    block_extract16(lst, tid, 16, wmin, &sum, &p16);
    if (tid == 0) tau[p] = p16 + PAD_TAU;
}

// K1: stream f2, MFMA distances, filter vs tau into dense FMAXV-filled float4
// cells surv4[row = gw*2+lh][col = p] (coalesced stores, no atomics).
__global__ __launch_bounds__(256) void k1_dist(
    const float* __restrict__ f2, const short* __restrict__ sel_bf,
    const float* __restrict__ sel2, const float* __restrict__ tau,
    float4* __restrict__ surv4)
{
    const int tid = threadIdx.x;
    const int lane = tid & 63, wid = tid >> 6;
    const int l31 = lane & 31, lh = lane >> 5;
    const int gw = blockIdx.x * 4 + wid;        // 0..6143

    bf16x8 sf0[4], sf1[4];
    load_selfrag(sel_bf, l31, lh, sf0, sf1);
    const float sel20 = sel2[l31], sel21 = sel2[l31 + 32];
    const float tau0 = tau[l31], tau1 = tau[l31 + 32];

    float4 v0 = make_float4(FMAXV, FMAXV, FMAXV, FMAXV);
    float4 v1 = v0;
    unsigned c0 = 0, c1 = 0;

    for (int t = 0; t < TPW; ++t) {
        const long n0 = (long)(gw * TPW + t) * NTILE;
        f32x16 acc0, acc1; float fs;
        tile_dist(f2 + n0 + l31, sf0, sf1, lh, acc0, acc1, fs);

#pragma unroll
        for (int i = 0; i < 16; ++i) {
            int r = (i & 3) + 8 * (i >> 2) + 4 * lh;
            float fr2 = __shfl(fs, r);
            float d0 = fmaxf(sel20 + fr2 - 2.f * acc0[i], 0.f);
            if (d0 <= tau0) {
                if (c0 == 0) v0.x = d0; else if (c0 == 1) v0.y = d0;
                else if (c0 == 2) v0.z = d0; else if (c0 == 3) v0.w = d0;
                ++c0;
            }
            float d1 = fmaxf(sel21 + fr2 - 2.f * acc1[i], 0.f);
            if (d1 <= tau1) {
                if (c1 == 0) v1.x = d1; else if (c1 == 1) v1.y = d1;
                else if (c1 == 2) v1.z = d1; else if (c1 == 3) v1.w = d1;
                ++c1;
            }
        }
    }
    float4* srow = surv4 + ((long)gw * 2 + lh) * 64;
    srow[l31]      = v0;   // p = l31
    srow[l31 + 32] = v1;   // p = l31 + 32
}

// k2a: 512 waves; wave reads 24 coalesced 1KB rows of surv4[W2][64];
// lane l screens column p=l into register top-16 -> cand2[p][wv][16].
__global__ __launch_bounds__(256) void k2a_screen(
    const float4* __restrict__ surv4, float* __restrict__ cand2)
{
    const int lane = threadIdx.x & 63;
    const int wv = blockIdx.x * 4 + (threadIdx.x >> 6);   // 0..511

    float lst[16];
#pragma unroll
    for (int j = 0; j < 16; ++j) lst[j] = FMAXV;
    float cm = FMAXV;

    const float4* base = surv4 + (long)wv * RPW * 64 + lane;
#pragma unroll 8
    for (int r = 0; r < RPW; ++r) {
        float4 v = base[r * 64];
        SCREEN(v.x, lst, cm);
        SCREEN(v.y, lst, cm);
        SCREEN(v.z, lst, cm);
        SCREEN(v.w, lst, cm);
    }

    float4* o = (float4*)(cand2 + ((long)lane * NW2A + wv) * 16);
#pragma unroll
    for (int q = 0; q < 4; ++q)
        o[q] = make_float4(lst[4*q], lst[4*q+1], lst[4*q+2], lst[4*q+3]);
}

// k2b: 64 blocks x 256 threads; block p: 8192 candidates -> exact top-16 sum.
__global__ __launch_bounds__(256) void k2b_select(
    const float* __restrict__ cand2, float* __restrict__ partial)
{
    const int p = blockIdx.x;
    const int tid = threadIdx.x;
    __shared__ unsigned long long wmin[4];
    const float4* base = (const float4*)(cand2 + (long)p * NW2A * 16);

    float lst[16];
#pragma unroll
    for (int j = 0; j < 16; ++j) lst[j] = FMAXV;
    float cm = FMAXV;
#pragma unroll
    for (int k = 0; k < NW2A * 16 / 4 / 256; ++k) {   // 8 coalesced float4
        float4 v = base[tid + k * 256];
        SCREEN(v.x, lst, cm);
        SCREEN(v.y, lst, cm);
        SCREEN(v.z, lst, cm);
        SCREEN(v.w, lst, cm);
    }
    float sum, p16;
    block_extract16(lst, tid, 4, wmin, &sum, &p16);
    if (tid == 0) partial[p] = sum;
}

__global__ void k3_final(const float* __restrict__ partial, float* __restrict__ out)
{
    float v = partial[threadIdx.x];   // 64 threads
#pragma unroll
    for (int off = 32; off; off >>= 1) v += __shfl_xor(v, off);
    if (threadIdx.x == 0) out[0] = -v / 1024.0f;
}

extern "C" void kernel_launch(void* const* d_in, const int* in_sizes, int n_in,
                              void* d_out, int out_size, void* d_ws, size_t ws_size,
                              hipStream_t stream)
{
    const float* f1   = (const float*)d_in[0];
    const float* f2   = (const float*)d_in[1];
    const int*   nidx = (const int*)d_in[3];     // negative_indices
    float* out = (float*)d_out;

    float4* surv4  = (float4*)d_ws;                        // 12288*64*16 B = 12.6 MB
    float*  dsP    = (float*)(surv4 + (long)W2 * 64);      // 64*65536*4 B = 16 MB
    float*  cand2  = dsP + (long)CD * NSAMP;               // 64*512*16 fl = 2 MB
    short*  sel_bf = (short*)(cand2 + (long)CD * NW2A * 16);  // 8 KB
    float*  sel2   = (float*)(sel_bf + CD * 64);
    float*  tau    = sel2 + CD;
    float*  partial = tau + CD;

    kA_pack   <<<CD,         64, 0, stream>>>(f1, nidx, sel_bf, sel2);
    kB_sample <<<KB_BLOCKS, 256, 0, stream>>>(f2, sel_bf, sel2, dsP);
    kC_tau    <<<CD,       1024, 0, stream>>>(dsP, tau);
    k1_dist   <<<K1_BLOCKS, 256, 0, stream>>>(f2, sel_bf, sel2, tau, surv4);
    k2a_screen<<<K2A_BLOCKS,256, 0, stream>>>(surv4, cand2);
    k2b_select<<<CD,        256, 0, stream>>>(cand2, partial);
    k3_final  <<<1,          64, 0, stream>>>(partial, out);
}

// Round 8
// 119.730 us; speedup vs baseline: 1.8282x; 1.5651x over previous
//
#include <hip/hip_runtime.h>
#include <cstdint>

#define CD 64
#define HWD 589824
#define NSAMP 8192
#define PAD_TAU 0.25f
#define K1_BLOCKS (HWD / 256)        // 2304
#define NROWS (K1_BLOCKS * 4 * 2)    // 18432 cell rows
#define NW2A 2048                    // k2a waves
#define K2A_BLOCKS (NW2A / 4)        // 512
#define RPW (NROWS / NW2A)           // 9 rows per k2a wave
#define FMAXV 3.402823466e+38f

#define AS1 __attribute__((address_space(1)))
#define AS3 __attribute__((address_space(3)))

typedef float f32x16 __attribute__((ext_vector_type(16)));
typedef short bf16x8 __attribute__((ext_vector_type(8)));

__device__ __forceinline__ short f2bf(float f) {
    unsigned u = __float_as_uint(f);
    u = u + 0x7FFFu + ((u >> 16) & 1u);   // RNE
    return (short)(u >> 16);
}

// exact 16-smallest screen (static indexing only)
#define SCREEN(d, lst, cm)                                                  \
    if ((d) < (cm)) {                                                       \
        bool rep = false;                                                   \
        _Pragma("unroll")                                                   \
        for (int j = 0; j < 16; ++j)                                        \
            if (!rep && lst[j] == (cm)) { lst[j] = (d); rep = true; }       \
        cm = lst[0];                                                        \
        _Pragma("unroll")                                                   \
        for (int j = 1; j < 16; ++j) cm = fmaxf(cm, lst[j]);                \
    }

// sorted top-4 insert (t0<=t1<=t2<=t3)
#define INS4(x)                                                             \
    if ((x) < t3) {                                                         \
        float _a = (x);                                                     \
        if (_a < t2) { t3 = t2;                                             \
            if (_a < t1) { t2 = t1;                                         \
                if (_a < t0) { t1 = t0; t0 = _a; } else t1 = _a;            \
            } else t2 = _a;                                                 \
        } else t3 = _a;                                                     \
    }

// block-wide exact 16-smallest extraction from per-thread lst[16].
__device__ __forceinline__ void block_extract16(
    float* lst, int tid, int nwaves, unsigned long long* wmin,
    float* sum_out, float* p16_out)
{
    const int lane = tid & 63, wid = tid >> 6;
    float sum = 0.f, last = 0.f;
    for (int r = 0; r < 16; ++r) {
        float mn = lst[0]; int a = 0;
#pragma unroll
        for (int j = 1; j < 16; ++j) if (lst[j] < mn) { mn = lst[j]; a = j; }
        unsigned long long key =
            ((unsigned long long)__float_as_uint(mn) << 32) | (unsigned)(tid * 16 + a);
#pragma unroll
        for (int off = 32; off; off >>= 1) {
            unsigned long long o = __shfl_xor(key, off);
            if (o < key) key = o;
        }
        if (lane == 0) wmin[wid] = key;
        __syncthreads();
        unsigned long long gk = wmin[0];
        for (int w = 1; w < nwaves; ++w) if (wmin[w] < gk) gk = wmin[w];
        last = __uint_as_float((unsigned)(gk >> 32));
        sum += last;
        int slot = (int)(gk & 0xFFFFFFFFu);
        if ((slot >> 4) == tid) {
#pragma unroll
            for (int j = 0; j < 16; ++j) if (j == (slot & 15)) lst[j] = FMAXV;
        }
        __syncthreads();
    }
    *sum_out = sum; *p16_out = last;
}

__device__ __forceinline__ void load_selfrag(
    const short* __restrict__ sel_bf, int l31, int lh, bf16x8* sf0, bf16x8* sf1)
{
#pragma unroll
    for (int ks = 0; ks < 4; ++ks) {
        sf0[ks] = *(const bf16x8*)(sel_bf + l31 * 64 + 16 * ks + 8 * lh);
        sf1[ks] = *(const bf16x8*)(sel_bf + (l31 + 32) * 64 + 16 * ks + 8 * lh);
    }
}

// VGPR-streaming tile engine (used by kB only; identical arithmetic to k1).
__device__ __forceinline__ void tile_dist(
    const float* __restrict__ fp,
    const bf16x8* __restrict__ sf0, const bf16x8* __restrict__ sf1,
    int lh, f32x16& acc0, f32x16& acc1, float& fs)
{
    fs = 0.f;
#pragma unroll
    for (int i = 0; i < 16; ++i) { acc0[i] = 0.f; acc1[i] = 0.f; }
#pragma unroll
    for (int ks = 0; ks < 4; ++ks) {
        float av[8];
#pragma unroll
        for (int j = 0; j < 8; ++j)
            av[j] = fp[(long)(16 * ks + 8 * lh + j) * HWD];
        bf16x8 af;
#pragma unroll
        for (int j = 0; j < 8; ++j) {
            fs += av[j] * av[j];
            af[j] = f2bf(av[j]);
        }
        acc0 = __builtin_amdgcn_mfma_f32_32x32x16_bf16(af, sf0[ks], acc0, 0, 0, 0);
        acc1 = __builtin_amdgcn_mfma_f32_32x32x16_bf16(af, sf1[ks], acc1, 0, 0, 0);
    }
    fs += __shfl_xor(fs, 32);
}

// kA: 64 blocks x 64 threads; thread k of block p loads one sel element.
__global__ __launch_bounds__(64) void kA_pack(
    const float* __restrict__ f1, const int* __restrict__ nidx,
    short* __restrict__ sel_bf, float* __restrict__ sel2)
{
    const int p = blockIdx.x, k = threadIdx.x;
    float v = f1[(long)k * HWD + nidx[p]];
    float s = v * v;
#pragma unroll
    for (int off = 32; off; off >>= 1) s += __shfl_xor(s, off);
    sel_bf[p * 64 + k] = f2bf(v);
    if (k == 0) sel2[p] = s;
}

// kB: 64 blocks x 4 waves = 256 waves; wave gw computes sample tile gw
// (cols gw*32..) and writes dsT[n][p].
__global__ __launch_bounds__(256) void kB_sample(
    const float* __restrict__ f2, const short* __restrict__ sel_bf,
    const float* __restrict__ sel2, float* __restrict__ dsT)
{
    const int tid = threadIdx.x;
    const int lane = tid & 63, wid = tid >> 6;
    const int l31 = lane & 31, lh = lane >> 5;
    const int gw = blockIdx.x * 4 + wid;      // 0..255
    const long n0 = (long)gw * 32;

    bf16x8 sf0[4], sf1[4];
    load_selfrag(sel_bf, l31, lh, sf0, sf1);
    const float sel20 = sel2[l31], sel21 = sel2[l31 + 32];

    f32x16 acc0, acc1; float fs;
    tile_dist(f2 + n0 + l31, sf0, sf1, lh, acc0, acc1, fs);

#pragma unroll
    for (int i = 0; i < 16; ++i) {
        int r = (i & 3) + 8 * (i >> 2) + 4 * lh;
        float fr2 = __shfl(fs, r);
        dsT[(n0 + r) * 64 + l31]      = fmaxf(sel20 + fr2 - 2.f * acc0[i], 0.f);
        dsT[(n0 + r) * 64 + 32 + l31] = fmaxf(sel21 + fr2 - 2.f * acc1[i], 0.f);
    }
}

// kC: 64 blocks x 256 thr; block p: 32 batched column loads/thread (L2-hot),
// screen, block-extract -> tau[p] (raw 16th; pad applied in k1).
__global__ __launch_bounds__(256) void kC_tau(
    const float* __restrict__ dsT, float* __restrict__ tau)
{
    const int p = blockIdx.x;
    const int tid = threadIdx.x;
    __shared__ unsigned long long wmin[4];

    float vals[32];
#pragma unroll
    for (int i = 0; i < 32; ++i)
        vals[i] = dsT[(long)(tid + i * 256) * 64 + p];   // independent loads

    float lst[16];
#pragma unroll
    for (int j = 0; j < 16; ++j) lst[j] = FMAXV;
    float cm = FMAXV;
#pragma unroll
    for (int i = 0; i < 32; ++i) { SCREEN(vals[i], lst, cm); }

    float sum, p16;
    block_extract16(lst, tid, 4, wmin, &sum, &p16);
    if (tid == 0) tau[p] = p16;
}

// K1: LDS-staged streaming filter. Block stages a [64][256] f32 tile of f2 via
// global_load_lds (16B width), then 4 waves compute 64 cols each via MFMA and
// filter vs tau into dense FMAXV-filled float4 cells (no atomics).
__global__ __launch_bounds__(256, 2) void k1_dist(
    const float* __restrict__ f2, const short* __restrict__ sel_bf,
    const float* __restrict__ sel2, const float* __restrict__ tau,
    float4* __restrict__ surv4)
{
    __shared__ float lds[CD][256];   // 64 KB
    const int tid = threadIdx.x;
    const int lane = tid & 63, wid = tid >> 6;
    const int l31 = lane & 31, lh = lane >> 5;
    const long n0 = (long)blockIdx.x * 256;

    // stage: wave wid stages k-rows [wid*16, wid*16+16), 1 KB per instr
    for (int kk = 0; kk < 16; ++kk) {
        int k = wid * 16 + kk;
        const float* gp = f2 + (long)k * HWD + n0 + lane * 4;
        __builtin_amdgcn_global_load_lds((const AS1 void*)gp,
                                         (AS3 void*)&lds[k][0], 16, 0, 0);
    }

    bf16x8 sf0[4], sf1[4];
    load_selfrag(sel_bf, l31, lh, sf0, sf1);
    const float sel20 = sel2[l31], sel21 = sel2[l31 + 32];
    const float tau0 = tau[l31] + PAD_TAU, tau1 = tau[l31 + 32] + PAD_TAU;

    __syncthreads();   // drain vmcnt -> tile ready

    float4 v0 = make_float4(FMAXV, FMAXV, FMAXV, FMAXV);
    float4 v1 = v0;
    unsigned c0 = 0, c1 = 0;

#pragma unroll
    for (int g = 0; g < 2; ++g) {
        const int col = wid * 64 + g * 32 + l31;
        float fs = 0.f;
        f32x16 a0, a1;
#pragma unroll
        for (int i = 0; i < 16; ++i) { a0[i] = 0.f; a1[i] = 0.f; }
#pragma unroll
        for (int ks = 0; ks < 4; ++ks) {
            bf16x8 af;
#pragma unroll
            for (int j = 0; j < 8; ++j) {
                float v = lds[16 * ks + 8 * lh + j][col];
                fs += v * v;
                af[j] = f2bf(v);
            }
            a0 = __builtin_amdgcn_mfma_f32_32x32x16_bf16(af, sf0[ks], a0, 0, 0, 0);
            a1 = __builtin_amdgcn_mfma_f32_32x32x16_bf16(af, sf1[ks], a1, 0, 0, 0);
        }
        fs += __shfl_xor(fs, 32);   // combine k-halves (same col)

#pragma unroll
        for (int i = 0; i < 16; ++i) {
            int r = (i & 3) + 8 * (i >> 2) + 4 * lh;
            float fr2 = __shfl(fs, r);
            float d0 = fmaxf(sel20 + fr2 - 2.f * a0[i], 0.f);
            if (d0 <= tau0) {
                if (c0 == 0) v0.x = d0; else if (c0 == 1) v0.y = d0;
                else if (c0 == 2) v0.z = d0; else if (c0 == 3) v0.w = d0;
                ++c0;
            }
            float d1 = fmaxf(sel21 + fr2 - 2.f * a1[i], 0.f);
            if (d1 <= tau1) {
                if (c1 == 0) v1.x = d1; else if (c1 == 1) v1.y = d1;
                else if (c1 == 2) v1.z = d1; else if (c1 == 3) v1.w = d1;
                ++c1;
            }
        }
    }
    float4* srow = surv4 + ((long)(blockIdx.x * 4 + wid) * 2 + lh) * 64;
    srow[l31]      = v0;   // p = l31
    srow[l31 + 32] = v1;   // p = l31 + 32
}

// k2a: 2048 waves; wave batch-loads 9 coalesced 1KB rows of surv4[NROWS][64];
// lane l owns p=l; sorted top-4 -> one float4 to cand2[p][wv].
__global__ __launch_bounds__(256) void k2a_screen(
    const float4* __restrict__ surv4, float4* __restrict__ cand2)
{
    const int lane = threadIdx.x & 63;
    const int wv = blockIdx.x * 4 + (threadIdx.x >> 6);   // 0..2047

    const float4* base = surv4 + (long)wv * RPW * 64 + lane;
    float4 b[RPW];
#pragma unroll
    for (int r = 0; r < RPW; ++r) b[r] = base[r * 64];    // independent loads

    float t0 = FMAXV, t1 = FMAXV, t2 = FMAXV, t3 = FMAXV;
#pragma unroll
    for (int r = 0; r < RPW; ++r) {
        INS4(b[r].x); INS4(b[r].y); INS4(b[r].z); INS4(b[r].w);
    }
    cand2[(long)lane * NW2A + wv] = make_float4(t0, t1, t2, t3);
}

// k2b: 64 blocks x 256 thr; block p: 8192 candidates -> exact top-16 sum.
__global__ __launch_bounds__(256) void k2b_select(
    const float4* __restrict__ cand2, float* __restrict__ partial)
{
    const int p = blockIdx.x;
    const int tid = threadIdx.x;
    __shared__ unsigned long long wmin[4];
    const float4* base = cand2 + (long)p * NW2A;

    float4 b[8];
#pragma unroll
    for (int k = 0; k < 8; ++k) b[k] = base[tid + k * 256];   // coalesced

    float lst[16];
#pragma unroll
    for (int j = 0; j < 16; ++j) lst[j] = FMAXV;
    float cm = FMAXV;
#pragma unroll
    for (int k = 0; k < 8; ++k) {
        SCREEN(b[k].x, lst, cm);
        SCREEN(b[k].y, lst, cm);
        SCREEN(b[k].z, lst, cm);
        SCREEN(b[k].w, lst, cm);
    }
    float sum, p16;
    block_extract16(lst, tid, 4, wmin, &sum, &p16);
    if (tid == 0) partial[p] = sum;
}

__global__ void k3_final(const float* __restrict__ partial, float* __restrict__ out)
{
    float v = partial[threadIdx.x];   // 64 threads
#pragma unroll
    for (int off = 32; off; off >>= 1) v += __shfl_xor(v, off);
    if (threadIdx.x == 0) out[0] = -v / 1024.0f;
}

extern "C" void kernel_launch(void* const* d_in, const int* in_sizes, int n_in,
                              void* d_out, int out_size, void* d_ws, size_t ws_size,
                              hipStream_t stream)
{
    const float* f1   = (const float*)d_in[0];
    const float* f2   = (const float*)d_in[1];
    const int*   nidx = (const int*)d_in[3];     // negative_indices
    float* out = (float*)d_out;

    float4* surv4  = (float4*)d_ws;                       // 18432*64*16 = 18.9 MB
    float4* cand2  = surv4 + (long)NROWS * 64;            // 64*2048*16  = 2.1 MB
    float*  dsT    = (float*)(cand2 + (long)CD * NW2A);   // 8192*64*4   = 2.1 MB
    short*  sel_bf = (short*)(dsT + (long)NSAMP * 64);    // 8 KB
    float*  sel2   = (float*)(sel_bf + CD * 64);
    float*  tau    = sel2 + CD;
    float*  partial = tau + CD;

    kA_pack   <<<CD,         64, 0, stream>>>(f1, nidx, sel_bf, sel2);
    kB_sample <<<CD,        256, 0, stream>>>(f2, sel_bf, sel2, dsT);
    kC_tau    <<<CD,        256, 0, stream>>>(dsT, tau);
    k1_dist   <<<K1_BLOCKS, 256, 0, stream>>>(f2, sel_bf, sel2, tau, surv4);
    k2a_screen<<<K2A_BLOCKS,256, 0, stream>>>(surv4, cand2);
    k2b_select<<<CD,        256, 0, stream>>>(cand2, partial);
    k3_final  <<<1,          64, 0, stream>>>(partial, out);
}

// Round 9
// 99.546 us; speedup vs baseline: 2.1989x; 1.2028x over previous
//
#include <hip/hip_runtime.h>
#include <cstdint>

#define CD 64
#define HWD 589824
#define NSAMP 8192
#define SWAVES (NSAMP / 32)          // 256 sample waves
#define PAD_TAU 0.25f
#define K1_BLOCKS (HWD / 128)        // 4608
#define NROWS (K1_BLOCKS * 4 * 2)    // 36864 cell rows
#define NW2A 2048                    // k2a waves
#define K2A_BLOCKS (NW2A / 4)        // 512
#define RPW (NROWS / NW2A)           // 18 rows per k2a wave
#define FMAXV 3.402823466e+38f

#define AS1 __attribute__((address_space(1)))
#define AS3 __attribute__((address_space(3)))

typedef float f32x16 __attribute__((ext_vector_type(16)));
typedef short bf16x8 __attribute__((ext_vector_type(8)));

__device__ __forceinline__ short f2bf(float f) {
    unsigned u = __float_as_uint(f);
    u = u + 0x7FFFu + ((u >> 16) & 1u);   // RNE
    return (short)(u >> 16);
}

// exact 16-smallest screen (static indexing only)
#define SCREEN(d, lst, cm)                                                  \
    if ((d) < (cm)) {                                                       \
        bool rep = false;                                                   \
        _Pragma("unroll")                                                   \
        for (int j = 0; j < 16; ++j)                                        \
            if (!rep && lst[j] == (cm)) { lst[j] = (d); rep = true; }       \
        cm = lst[0];                                                        \
        _Pragma("unroll")                                                   \
        for (int j = 1; j < 16; ++j) cm = fmaxf(cm, lst[j]);                \
    }

// sorted top-4 insert (t0<=t1<=t2<=t3)
#define INS4(x)                                                             \
    if ((x) < t3) {                                                         \
        float _a = (x);                                                     \
        if (_a < t2) { t3 = t2;                                             \
            if (_a < t1) { t2 = t1;                                         \
                if (_a < t0) { t1 = t0; t0 = _a; } else t1 = _a;            \
            } else t2 = _a;                                                 \
        } else t3 = _a;                                                     \
    }

// block-wide exact 16-smallest extraction from per-thread lst[16].
__device__ __forceinline__ void block_extract16(
    float* lst, int tid, int nwaves, unsigned long long* wmin,
    float* sum_out, float* p16_out)
{
    const int lane = tid & 63, wid = tid >> 6;
    float sum = 0.f, last = 0.f;
    for (int r = 0; r < 16; ++r) {
        float mn = lst[0]; int a = 0;
#pragma unroll
        for (int j = 1; j < 16; ++j) if (lst[j] < mn) { mn = lst[j]; a = j; }
        unsigned long long key =
            ((unsigned long long)__float_as_uint(mn) << 32) | (unsigned)(tid * 16 + a);
#pragma unroll
        for (int off = 32; off; off >>= 1) {
            unsigned long long o = __shfl_xor(key, off);
            if (o < key) key = o;
        }
        if (lane == 0) wmin[wid] = key;
        __syncthreads();
        unsigned long long gk = wmin[0];
        for (int w = 1; w < nwaves; ++w) if (wmin[w] < gk) gk = wmin[w];
        last = __uint_as_float((unsigned)(gk >> 32));
        sum += last;
        int slot = (int)(gk & 0xFFFFFFFFu);
        if ((slot >> 4) == tid) {
#pragma unroll
            for (int j = 0; j < 16; ++j) if (j == (slot & 15)) lst[j] = FMAXV;
        }
        __syncthreads();
    }
    *sum_out = sum; *p16_out = last;
}

// VGPR-streaming tile engine (kB); arithmetic must stay bit-identical to k1.
__device__ __forceinline__ void tile_dist(
    const float* __restrict__ fp,
    const bf16x8* __restrict__ sf0, const bf16x8* __restrict__ sf1,
    int lh, f32x16& acc0, f32x16& acc1, float& fs)
{
    fs = 0.f;
#pragma unroll
    for (int i = 0; i < 16; ++i) { acc0[i] = 0.f; acc1[i] = 0.f; }
#pragma unroll
    for (int ks = 0; ks < 4; ++ks) {
        float av[8];
#pragma unroll
        for (int j = 0; j < 8; ++j)
            av[j] = fp[(long)(16 * ks + 8 * lh + j) * HWD];
        bf16x8 af;
#pragma unroll
        for (int j = 0; j < 8; ++j) {
            fs += av[j] * av[j];
            af[j] = f2bf(av[j]);
        }
        acc0 = __builtin_amdgcn_mfma_f32_32x32x16_bf16(af, sf0[ks], acc0, 0, 0, 0);
        acc1 = __builtin_amdgcn_mfma_f32_32x32x16_bf16(af, sf1[ks], acc1, 0, 0, 0);
    }
    fs += __shfl_xor(fs, 32);   // combine k-halves (same column n)
}

// kB: 64 blocks x 256 thr. Phase 1: every block packs sel in LDS (L2-hot
// gathers, redundant); block 0 publishes bf16 pack + ||sel||^2. Phase 2:
// wave gw computes sample tile gw (32 cols) and emits top-4 cells.
__global__ __launch_bounds__(256) void kB_prep(
    const float* __restrict__ f1, const float* __restrict__ f2,
    const int* __restrict__ nidx, short* __restrict__ sel_bf,
    float* __restrict__ sel2, float4* __restrict__ scand4)
{
    __shared__ float selk[CD][CD];     // [p][k], 16 KB
    __shared__ float sel2s[CD];
    const int tid = threadIdx.x;
    const int lane = tid & 63, wid = tid >> 6;
    const int l31 = lane & 31, lh = lane >> 5;

    // phase 1: pack (4096 gathers, 16 per thread)
#pragma unroll
    for (int q = 0; q < 16; ++q) {
        int idx = q * 256 + tid;
        int p = idx >> 6, k = idx & 63;
        selk[p][k] = f1[(long)k * HWD + nidx[p]];
    }
    __syncthreads();
    if (tid < CD) {
        float s = 0.f;
#pragma unroll
        for (int k = 0; k < CD; ++k) s += selk[tid][k] * selk[tid][k];
        sel2s[tid] = s;
        if (blockIdx.x == 0) {
            sel2[tid] = s;
            short row[CD];
#pragma unroll
            for (int k = 0; k < CD; ++k) row[k] = f2bf(selk[tid][k]);
#pragma unroll
            for (int k = 0; k < CD; ++k) sel_bf[tid * CD + k] = row[k];
        }
    }
    __syncthreads();

    // build fragments from LDS (same bits as k1's global bf16 pack)
    bf16x8 sf0[4], sf1[4];
#pragma unroll
    for (int ks = 0; ks < 4; ++ks) {
#pragma unroll
        for (int j = 0; j < 8; ++j) {
            sf0[ks][j] = f2bf(selk[l31][16 * ks + 8 * lh + j]);
            sf1[ks][j] = f2bf(selk[l31 + 32][16 * ks + 8 * lh + j]);
        }
    }
    const float sel20 = sel2s[l31], sel21 = sel2s[l31 + 32];

    // phase 2: sample tile
    const int gw = blockIdx.x * 4 + wid;      // 0..255
    const long n0 = (long)gw * 32;
    f32x16 acc0, acc1; float fs;
    tile_dist(f2 + n0 + l31, sf0, sf1, lh, acc0, acc1, fs);

    float t0 = FMAXV, t1 = FMAXV, t2 = FMAXV, t3 = FMAXV;
    float u0 = FMAXV, u1 = FMAXV, u2 = FMAXV, u3 = FMAXV;
#pragma unroll
    for (int i = 0; i < 16; ++i) {
        int r = (i & 3) + 8 * (i >> 2) + 4 * lh;
        float fr2 = __shfl(fs, r);
        float d0 = fmaxf(sel20 + fr2 - 2.f * acc0[i], 0.f);
        INS4(d0);
        float d1 = fmaxf(sel21 + fr2 - 2.f * acc1[i], 0.f);
        { float s0=t0,s1=t1,s2=t2,s3=t3; t0=u0;t1=u1;t2=u2;t3=u3;
          INS4(d1); u0=t0;u1=t1;u2=t2;u3=t3; t0=s0;t1=s1;t2=s2;t3=s3; }
    }
    float4* srow = scand4 + ((long)gw * 2 + lh) * 64;
    srow[l31]      = make_float4(t0, t1, t2, t3);
    srow[l31 + 32] = make_float4(u0, u1, u2, u3);
}

// kC: block p merges 512 sample cells -> 16th smallest -> tau[p] (pad folded).
__global__ __launch_bounds__(256) void kC_tau(
    const float4* __restrict__ scand4, float* __restrict__ tau)
{
    const int p = blockIdx.x;
    const int tid = threadIdx.x;
    __shared__ unsigned long long wmin[4];

    float4 a = scand4[(long)tid * 64 + p];
    float4 b = scand4[(long)(tid + 256) * 64 + p];

    float lst[16];
#pragma unroll
    for (int j = 0; j < 16; ++j) lst[j] = FMAXV;
    float cm = FMAXV;
    SCREEN(a.x, lst, cm); SCREEN(a.y, lst, cm);
    SCREEN(a.z, lst, cm); SCREEN(a.w, lst, cm);
    SCREEN(b.x, lst, cm); SCREEN(b.y, lst, cm);
    SCREEN(b.z, lst, cm); SCREEN(b.w, lst, cm);

    float sum, p16;
    block_extract16(lst, tid, 4, wmin, &sum, &p16);
    if (tid == 0) tau[p] = p16 + PAD_TAU;
}

// K1: 4608 blocks, 4/CU. Stage [64][128] f32 tile (32 KB) via global_load_lds
// (2 rows per instr, per-lane global addr), MFMA, filter vs tau into dense
// FMAXV-filled float4 cells (no atomics).
__global__ __launch_bounds__(256, 4) void k1_dist(
    const float* __restrict__ f2, const short* __restrict__ sel_bf,
    const float* __restrict__ sel2, const float* __restrict__ tau,
    float4* __restrict__ surv4)
{
    __shared__ float lds[CD][128];   // 32 KB
    const int tid = threadIdx.x;
    const int lane = tid & 63, wid = tid >> 6;
    const int l31 = lane & 31, lh = lane >> 5;
    const long n0 = (long)blockIdx.x * 128;

    // stage: wave wid stages rows [wid*16, wid*16+16); 2 rows per instr
    {
        const int srow2 = lane >> 5;
        const int scol  = (lane & 31) * 4;
#pragma unroll
        for (int kk = 0; kk < 8; ++kk) {
            int k = wid * 16 + kk * 2;
            const float* gp = f2 + (long)(k + srow2) * HWD + n0 + scol;
            __builtin_amdgcn_global_load_lds((const AS1 void*)gp,
                                             (AS3 void*)&lds[k][0], 16, 0, 0);
        }
    }

    bf16x8 sf0[4], sf1[4];
#pragma unroll
    for (int ks = 0; ks < 4; ++ks) {
        sf0[ks] = *(const bf16x8*)(sel_bf + l31 * CD + 16 * ks + 8 * lh);
        sf1[ks] = *(const bf16x8*)(sel_bf + (l31 + 32) * CD + 16 * ks + 8 * lh);
    }
    const float sel20 = sel2[l31], sel21 = sel2[l31 + 32];
    const float tau0 = tau[l31], tau1 = tau[l31 + 32];

    __syncthreads();   // drain vmcnt -> tile ready

    const int col = wid * 32 + l31;
    float fs = 0.f;
    f32x16 a0, a1;
#pragma unroll
    for (int i = 0; i < 16; ++i) { a0[i] = 0.f; a1[i] = 0.f; }
#pragma unroll
    for (int ks = 0; ks < 4; ++ks) {
        bf16x8 af;
#pragma unroll
        for (int j = 0; j < 8; ++j) {
            float v = lds[16 * ks + 8 * lh + j][col];
            fs += v * v;
            af[j] = f2bf(v);
        }
        a0 = __builtin_amdgcn_mfma_f32_32x32x16_bf16(af, sf0[ks], a0, 0, 0, 0);
        a1 = __builtin_amdgcn_mfma_f32_32x32x16_bf16(af, sf1[ks], a1, 0, 0, 0);
    }
    fs += __shfl_xor(fs, 32);   // combine k-halves (same col)

    float4 v0 = make_float4(FMAXV, FMAXV, FMAXV, FMAXV);
    float4 v1 = v0;
    unsigned c0 = 0, c1 = 0;
#pragma unroll
    for (int i = 0; i < 16; ++i) {
        int r = (i & 3) + 8 * (i >> 2) + 4 * lh;
        float fr2 = __shfl(fs, r);
        float d0 = fmaxf(sel20 + fr2 - 2.f * a0[i], 0.f);
        if (d0 <= tau0) {
            if (c0 == 0) v0.x = d0; else if (c0 == 1) v0.y = d0;
            else if (c0 == 2) v0.z = d0; else if (c0 == 3) v0.w = d0;
            ++c0;
        }
        float d1 = fmaxf(sel21 + fr2 - 2.f * a1[i], 0.f);
        if (d1 <= tau1) {
            if (c1 == 0) v1.x = d1; else if (c1 == 1) v1.y = d1;
            else if (c1 == 2) v1.z = d1; else if (c1 == 3) v1.w = d1;
            ++c1;
        }
    }
    float4* srow = surv4 + ((long)(blockIdx.x * 4 + wid) * 2 + lh) * 64;
    srow[l31]      = v0;   // p = l31
    srow[l31 + 32] = v1;   // p = l31 + 32
}

// k2a: 2048 waves; wave batch-loads 18 coalesced 1KB rows of surv4[NROWS][64];
// lane l owns p=l; sorted top-4 -> one float4 to cand2[p][wv].
__global__ __launch_bounds__(256) void k2a_screen(
    const float4* __restrict__ surv4, float4* __restrict__ cand2)
{
    const int lane = threadIdx.x & 63;
    const int wv = blockIdx.x * 4 + (threadIdx.x >> 6);   // 0..2047

    const float4* base = surv4 + (long)wv * RPW * 64 + lane;
    float4 b[RPW];
#pragma unroll
    for (int r = 0; r < RPW; ++r) b[r] = base[r * 64];    // independent loads

    float t0 = FMAXV, t1 = FMAXV, t2 = FMAXV, t3 = FMAXV;
#pragma unroll
    for (int r = 0; r < RPW; ++r) {
        INS4(b[r].x); INS4(b[r].y); INS4(b[r].z); INS4(b[r].w);
    }
    cand2[(long)lane * NW2A + wv] = make_float4(t0, t1, t2, t3);
}

// k2b: 64 blocks x 256 thr; block p: 8192 candidates -> exact top-16 sum.
__global__ __launch_bounds__(256) void k2b_select(
    const float4* __restrict__ cand2, float* __restrict__ partial)
{
    const int p = blockIdx.x;
    const int tid = threadIdx.x;
    __shared__ unsigned long long wmin[4];
    const float4* base = cand2 + (long)p * NW2A;

    float4 b[8];
#pragma unroll
    for (int k = 0; k < 8; ++k) b[k] = base[tid + k * 256];   // coalesced

    float lst[16];
#pragma unroll
    for (int j = 0; j < 16; ++j) lst[j] = FMAXV;
    float cm = FMAXV;
#pragma unroll
    for (int k = 0; k < 8; ++k) {
        SCREEN(b[k].x, lst, cm);
        SCREEN(b[k].y, lst, cm);
        SCREEN(b[k].z, lst, cm);
        SCREEN(b[k].w, lst, cm);
    }
    float sum, p16;
    block_extract16(lst, tid, 4, wmin, &sum, &p16);
    if (tid == 0) partial[p] = sum;
}

__global__ void k3_final(const float* __restrict__ partial, float* __restrict__ out)
{
    float v = partial[threadIdx.x];   // 64 threads
#pragma unroll
    for (int off = 32; off; off >>= 1) v += __shfl_xor(v, off);
    if (threadIdx.x == 0) out[0] = -v / 1024.0f;
}

extern "C" void kernel_launch(void* const* d_in, const int* in_sizes, int n_in,
                              void* d_out, int out_size, void* d_ws, size_t ws_size,
                              hipStream_t stream)
{
    const float* f1   = (const float*)d_in[0];
    const float* f2   = (const float*)d_in[1];
    const int*   nidx = (const int*)d_in[3];     // negative_indices
    float* out = (float*)d_out;

    float4* surv4  = (float4*)d_ws;                        // 36864*64*16 = 37.7 MB
    float4* cand2  = surv4 + (long)NROWS * 64;             // 64*2048*16  = 2.1 MB
    float4* scand4 = cand2 + (long)CD * NW2A;              // 512*64*16   = 0.5 MB
    short*  sel_bf = (short*)(scand4 + (long)SWAVES * 2 * 64);   // 8 KB
    float*  sel2   = (float*)(sel_bf + CD * CD);
    float*  tau    = sel2 + CD;
    float*  partial = tau + CD;

    kB_prep   <<<CD,        256, 0, stream>>>(f1, f2, nidx, sel_bf, sel2, scand4);
    kC_tau    <<<CD,        256, 0, stream>>>(scand4, tau);
    k1_dist   <<<K1_BLOCKS, 256, 0, stream>>>(f2, sel_bf, sel2, tau, surv4);
    k2a_screen<<<K2A_BLOCKS,256, 0, stream>>>(surv4, cand2);
    k2b_select<<<CD,        256, 0, stream>>>(cand2, partial);
    k3_final  <<<1,          64, 0, stream>>>(partial, out);
}

// Round 10
// 83.159 us; speedup vs baseline: 2.6321x; 1.1971x over previous
//
#include <hip/hip_runtime.h>
#include <cstdint>

#define CD 64
#define HWD 589824
#define K1_BLOCKS (HWD / 128)        // 4608
#define FMAXV 3.402823466e+38f

#define AS1 __attribute__((address_space(1)))
#define AS3 __attribute__((address_space(3)))

typedef float f32x16 __attribute__((ext_vector_type(16)));
typedef short bf16x8 __attribute__((ext_vector_type(8)));

__device__ __forceinline__ short f2bf(float f) {
    unsigned u = __float_as_uint(f);
    u = u + 0x7FFFu + ((u >> 16) & 1u);   // RNE
    return (short)(u >> 16);
}

// sorted top-4 insert: t.x <= t.y <= t.z <= t.w
__device__ __forceinline__ void ins4(float4& t, float x) {
    if (x < t.w) {
        if (x < t.z) { t.w = t.z;
            if (x < t.y) { t.z = t.y;
                if (x < t.x) { t.y = t.x; t.x = x; } else t.y = x;
            } else t.z = x;
        } else t.w = x;
    }
}

// kA: 64 blocks x 64 thr; thread k of block p loads one sel element.
// Also resets the completion ticket for this launch.
__global__ __launch_bounds__(64) void kA_pack(
    const float* __restrict__ f1, const int* __restrict__ nidx,
    short* __restrict__ sel_bf, float* __restrict__ sel2,
    unsigned* __restrict__ ticket)
{
    const int p = blockIdx.x, k = threadIdx.x;
    if (p == 0 && k == 0) *ticket = 0u;
    float v = f1[(long)k * HWD + nidx[p]];
    float s = v * v;
#pragma unroll
    for (int off = 32; off; off >>= 1) s += __shfl_xor(s, off);
    sel_bf[p * CD + k] = f2bf(v);
    if (k == 0) sel2[p] = s;
}

// k1: 4608 blocks, 4/CU. Stage [64][128] f32 tile via global_load_lds,
// MFMA distances, per-lane sorted top-4 per p, lh-merge (shfl), 4-wave
// LDS merge -> cells[block][p] = top-4 of d(p, n) over the block's 128
// columns. No tau, no atomics, 1 KB coalesced store per block.
__global__ __launch_bounds__(256, 4) void k1_topk(
    const float* __restrict__ f2, const short* __restrict__ sel_bf,
    const float* __restrict__ sel2, float4* __restrict__ cells)
{
    __shared__ float lds[CD][128];   // 32 KB
    __shared__ float4 lm[4][CD];     // 4 KB
    const int tid = threadIdx.x;
    const int lane = tid & 63, wid = tid >> 6;
    const int l31 = lane & 31, lh = lane >> 5;
    const long n0 = (long)blockIdx.x * 128;

    // stage: wave wid stages rows [wid*16, wid*16+16); 2 rows per instr
    {
        const int srow2 = lane >> 5;
        const int scol  = (lane & 31) * 4;
#pragma unroll
        for (int kk = 0; kk < 8; ++kk) {
            int k = wid * 16 + kk * 2;
            const float* gp = f2 + (long)(k + srow2) * HWD + n0 + scol;
            __builtin_amdgcn_global_load_lds((const AS1 void*)gp,
                                             (AS3 void*)&lds[k][0], 16, 0, 0);
        }
    }

    bf16x8 sf0[4], sf1[4];
#pragma unroll
    for (int ks = 0; ks < 4; ++ks) {
        sf0[ks] = *(const bf16x8*)(sel_bf + l31 * CD + 16 * ks + 8 * lh);
        sf1[ks] = *(const bf16x8*)(sel_bf + (l31 + 32) * CD + 16 * ks + 8 * lh);
    }
    const float sel20 = sel2[l31], sel21 = sel2[l31 + 32];

    __syncthreads();   // tile ready

    const int col = wid * 32 + l31;
    float fs = 0.f;
    f32x16 a0, a1;
#pragma unroll
    for (int i = 0; i < 16; ++i) { a0[i] = 0.f; a1[i] = 0.f; }
#pragma unroll
    for (int ks = 0; ks < 4; ++ks) {
        bf16x8 af;
#pragma unroll
        for (int j = 0; j < 8; ++j) {
            float v = lds[16 * ks + 8 * lh + j][col];
            fs += v * v;
            af[j] = f2bf(v);
        }
        a0 = __builtin_amdgcn_mfma_f32_32x32x16_bf16(af, sf0[ks], a0, 0, 0, 0);
        a1 = __builtin_amdgcn_mfma_f32_32x32x16_bf16(af, sf1[ks], a1, 0, 0, 0);
    }
    fs += __shfl_xor(fs, 32);   // combine k-halves (same col)

    float4 t = make_float4(FMAXV, FMAXV, FMAXV, FMAXV);
    float4 u = t;
#pragma unroll
    for (int i = 0; i < 16; ++i) {
        int r = (i & 3) + 8 * (i >> 2) + 4 * lh;
        float fr2 = __shfl(fs, r);
        ins4(t, fmaxf(sel20 + fr2 - 2.f * a0[i], 0.f));   // p = l31
        ins4(u, fmaxf(sel21 + fr2 - 2.f * a1[i], 0.f));   // p = l31+32
    }

    // merge the two lh row-halves (lanes l and l^32 hold the same p)
    {
        float4 o;
        o.x = __shfl_xor(t.x, 32); o.y = __shfl_xor(t.y, 32);
        o.z = __shfl_xor(t.z, 32); o.w = __shfl_xor(t.w, 32);
        ins4(t, o.x); ins4(t, o.y); ins4(t, o.z); ins4(t, o.w);
        o.x = __shfl_xor(u.x, 32); o.y = __shfl_xor(u.y, 32);
        o.z = __shfl_xor(u.z, 32); o.w = __shfl_xor(u.w, 32);
        ins4(u, o.x); ins4(u, o.y); ins4(u, o.z); ins4(u, o.w);
    }
    if (lh == 0) { lm[wid][l31] = t; lm[wid][l31 + 32] = u; }
    __syncthreads();

    // wave 0 merges the 4 waves' lists -> top-4 over 128 cols per p
    if (tid < CD) {
        float4 m  = lm[0][tid];
        float4 b1 = lm[1][tid], b2 = lm[2][tid], b3 = lm[3][tid];
        ins4(m, b1.x); ins4(m, b1.y); ins4(m, b1.z); ins4(m, b1.w);
        ins4(m, b2.x); ins4(m, b2.y); ins4(m, b2.z); ins4(m, b2.w);
        ins4(m, b3.x); ins4(m, b3.y); ins4(m, b3.z); ins4(m, b3.w);
        cells[(long)blockIdx.x * CD + tid] = m;
    }
}

// k2: 64 blocks x 1024 thr; block p: per-thread sorted top-4 over its 4-5
// rows of cells[.][p], then 16 rounds of block-wide min extraction (local
// min is always t.x -> shift on extract). Last finished block (ticket)
// does the deterministic final sum.
__global__ __launch_bounds__(1024) void k2_sel(
    const float4* __restrict__ cells, float* __restrict__ partial,
    unsigned* __restrict__ ticket, float* __restrict__ out)
{
    const int p = blockIdx.x;
    const int tid = threadIdx.x;
    const int lane = tid & 63, wid = tid >> 6;
    __shared__ unsigned long long wmin[16];

    float4 b0 = cells[(long)(tid)        * CD + p];
    float4 b1 = cells[(long)(tid + 1024) * CD + p];
    float4 b2 = cells[(long)(tid + 2048) * CD + p];
    float4 b3 = cells[(long)(tid + 3072) * CD + p];
    float4 b4 = (tid < K1_BLOCKS - 4096)
                ? cells[(long)(tid + 4096) * CD + p]
                : make_float4(FMAXV, FMAXV, FMAXV, FMAXV);

    float4 t = make_float4(FMAXV, FMAXV, FMAXV, FMAXV);
    ins4(t, b0.x); ins4(t, b0.y); ins4(t, b0.z); ins4(t, b0.w);
    ins4(t, b1.x); ins4(t, b1.y); ins4(t, b1.z); ins4(t, b1.w);
    ins4(t, b2.x); ins4(t, b2.y); ins4(t, b2.z); ins4(t, b2.w);
    ins4(t, b3.x); ins4(t, b3.y); ins4(t, b3.z); ins4(t, b3.w);
    ins4(t, b4.x); ins4(t, b4.y); ins4(t, b4.z); ins4(t, b4.w);

    float sum = 0.f;
    for (int rd = 0; rd < 16; ++rd) {
        unsigned long long key =
            ((unsigned long long)__float_as_uint(t.x) << 32) | (unsigned)tid;
#pragma unroll
        for (int off = 32; off; off >>= 1) {
            unsigned long long o = __shfl_xor(key, off);
            if (o < key) key = o;
        }
        if (lane == 0) wmin[wid] = key;
        __syncthreads();
        unsigned long long gk = wmin[0];
#pragma unroll
        for (int w = 1; w < 16; ++w) if (wmin[w] < gk) gk = wmin[w];
        sum += __uint_as_float((unsigned)(gk >> 32));
        if ((unsigned)(gk & 0xFFFFFFFFu) == (unsigned)tid) {
            t.x = t.y; t.y = t.z; t.z = t.w; t.w = FMAXV;   // pop local min
        }
        __syncthreads();
    }

    if (tid == 0) {
        partial[p] = sum;
        __threadfence();
        unsigned tk = atomicAdd(ticket, 1u);
        if (tk == CD - 1) {          // last block: deterministic ordered sum
            __threadfence();
            float s = 0.f;
            const volatile float* vp = partial;
            for (int q = 0; q < CD; ++q) s += vp[q];
            out[0] = -s / 1024.0f;
        }
    }
}

extern "C" void kernel_launch(void* const* d_in, const int* in_sizes, int n_in,
                              void* d_out, int out_size, void* d_ws, size_t ws_size,
                              hipStream_t stream)
{
    const float* f1   = (const float*)d_in[0];
    const float* f2   = (const float*)d_in[1];
    const int*   nidx = (const int*)d_in[3];     // negative_indices
    float* out = (float*)d_out;

    float4*   cells   = (float4*)d_ws;                      // 4608*64*16 = 4.7 MB
    short*    sel_bf  = (short*)(cells + (long)K1_BLOCKS * CD);   // 8 KB
    float*    sel2    = (float*)(sel_bf + CD * CD);
    float*    partial = sel2 + CD;
    unsigned* ticket  = (unsigned*)(partial + CD);

    kA_pack<<<CD,         64, 0, stream>>>(f1, nidx, sel_bf, sel2, ticket);
    k1_topk<<<K1_BLOCKS, 256, 0, stream>>>(f2, sel_bf, sel2, cells);
    k2_sel <<<CD,       1024, 0, stream>>>(cells, partial, ticket, out);
}